// Round 1
// baseline (220.302 us; speedup 1.0000x reference)
//
#include <hip/hip_runtime.h>

// Problem constants
#define LSEQ 1024
#define DMODEL 1024
#define NHEADS 16
#define FDIM 16
#define HDIM 64
#define CHUNK 64
#define NCHUNK 16

typedef __attribute__((ext_vector_type(8))) short short8;   // 8 bf16 (4 VGPRs)
typedef __attribute__((ext_vector_type(4))) float floatx4;  // MFMA acc

__device__ __forceinline__ float bf2f(unsigned short u) {
    unsigned int x = ((unsigned int)u) << 16;
    return __builtin_bit_cast(float, x);
}
__device__ __forceinline__ unsigned short f2bf(float f) {
    unsigned int x = __builtin_bit_cast(unsigned int, f);
    unsigned int r = (x + 0x7fffu + ((x >> 16) & 1u)) >> 16;
    return (unsigned short)r;
}

// Per-block dtype detector: samples 1024 ushorts of Wq. bf16 data -> exponents
// cluster tightly (bad ~0%); fp32-as-ushort -> half the samples are uniform
// mantissa bits (bad ~30%+). Returns 1 if inputs are fp32.
__device__ __forceinline__ int block_detect_fp32(const unsigned short* wq) {
    __shared__ int cnt;
    if (threadIdx.x == 0) cnt = 0;
    __syncthreads();
    int bad = 0;
    for (int i = threadIdx.x; i < 1024; i += blockDim.x) {
        int e = (wq[i] >> 7) & 0xFF;
        if (e >= 143 || (e > 0 && e <= 80)) bad++;
    }
    if (bad) atomicAdd(&cnt, bad);
    __syncthreads();
    return cnt > 128;
}

// Workspace layout (ushort indices):
//   qbB @0        (262144)   bf16 q  [1024][256]
//   kbB @262144   (262144)   bf16 k  [1024][256]
//   vbB @524288   (1048576)  bf16 v  [1024][1024]
//   ybB @1572864  (1048576)  bf16 y  [1024][1024]
//   then fp32 partials (byte offset 5242880):
//   numW  [256][2][64][64] fp32   (2097152 floats)
//   denW  [256][2][64]     fp32   (32768 floats)
//   flagW [256]            int
#define U_QB   0
#define U_KB   262144
#define U_VB   524288
#define U_YB   1572864
#define U_END  2621440

#define MFMA(a, b, c) __builtin_amdgcn_mfma_f32_16x16x32_bf16((a), (b), (c), 0, 0, 0)

// ---------------------------------------------------------------------------
// Pipelined 64x64 GEMM tile body: C(64x64) = A[arow0:+64] @ B[brow0:+64]^T,
// lda = ldb = 1024, K = 1024, BK = 128. Iter k+1's global loads issue right
// after the LDS-ready barrier, overlapping the 16 MFMAs; the vmcnt drain
// lands at the NEXT iteration's LDS write instead of serializing each iter.
// acc order: 00,01,10,11 (mi*2+ni).
// ---------------------------------------------------------------------------
__device__ __forceinline__ void gemm64_body(
    unsigned short (&As)[64][136], unsigned short (&Bs)[64][136],
    const void* Araw, int a_fp32, int arow0,
    const void* Braw, int b_fp32, int brow0, floatx4 acc[4]) {
    int t = threadIdx.x;
    int r = t >> 2, c0 = (t & 3) * 32;
    int wave = t >> 6, lane = t & 63;
    int ml = lane & 15, q4 = lane >> 4;
    int mq = (wave >> 1) * 32, nq = (wave & 1) * 32;
    #pragma unroll
    for (int i = 0; i < 4; ++i) acc[i] = (floatx4){0.f, 0.f, 0.f, 0.f};

    short8 av[4], bv[4], av2[4], bv2[4];
    auto stage = [&](int k0, short8* a, short8* b) {
        if (!a_fp32) {
            const unsigned short* Ap = (const unsigned short*)Araw + (size_t)(arow0 + r) * DMODEL + k0 + c0;
            #pragma unroll
            for (int j = 0; j < 4; ++j) a[j] = *(const short8*)(Ap + j * 8);
        } else {
            const float* Ap = (const float*)Araw + (size_t)(arow0 + r) * DMODEL + k0 + c0;
            #pragma unroll
            for (int j = 0; j < 4; ++j)
                #pragma unroll
                for (int u = 0; u < 8; ++u) a[j][u] = (short)f2bf(Ap[j * 8 + u]);
        }
        if (!b_fp32) {
            const unsigned short* Bp = (const unsigned short*)Braw + (size_t)(brow0 + r) * DMODEL + k0 + c0;
            #pragma unroll
            for (int j = 0; j < 4; ++j) b[j] = *(const short8*)(Bp + j * 8);
        } else {
            const float* Bp = (const float*)Braw + (size_t)(brow0 + r) * DMODEL + k0 + c0;
            #pragma unroll
            for (int j = 0; j < 4; ++j)
                #pragma unroll
                for (int u = 0; u < 8; ++u) b[j][u] = (short)f2bf(Bp[j * 8 + u]);
        }
    };

    stage(0, av, bv);
    for (int k0 = 0; k0 < DMODEL; k0 += 128) {
        __syncthreads();   // previous iter's LDS reads done
        #pragma unroll
        for (int j = 0; j < 4; ++j) {
            *(short8*)&As[r][c0 + j * 8] = av[j];
            *(short8*)&Bs[r][c0 + j * 8] = bv[j];
        }
        __syncthreads();   // LDS ready
        if (k0 + 128 < DMODEL) stage(k0 + 128, av2, bv2);   // overlap with MFMA
        #pragma unroll
        for (int kk = 0; kk < 4; ++kk) {
            short8 a0 = *(const short8*)&As[mq + ml][kk * 32 + q4 * 8];
            short8 a1 = *(const short8*)&As[mq + 16 + ml][kk * 32 + q4 * 8];
            short8 b0 = *(const short8*)&Bs[nq + ml][kk * 32 + q4 * 8];
            short8 b1 = *(const short8*)&Bs[nq + 16 + ml][kk * 32 + q4 * 8];
            acc[0] = MFMA(a0, b0, acc[0]); acc[1] = MFMA(a0, b1, acc[1]);
            acc[2] = MFMA(a1, b0, acc[2]); acc[3] = MFMA(a1, b1, acc[3]);
        }
        #pragma unroll
        for (int j = 0; j < 4; ++j) { av[j] = av2[j]; bv[j] = bv2[j]; }
    }
}

// ---------------------------------------------------------------------------
// Kernel 1: QKV projection. grid (24, 16): nb 0..3 q, 4..7 k, 8..23 v.
// Also zeroes the 256 combine flags (workspace is poisoned between reps;
// stream order makes the zeros visible to flash_attn).
// ---------------------------------------------------------------------------
__global__ __launch_bounds__(256) void qkv_gemm(
    const void* __restrict__ hidR, const void* __restrict__ WqR,
    const void* __restrict__ WkR, const void* __restrict__ WvR,
    unsigned short* __restrict__ qb, unsigned short* __restrict__ kb,
    unsigned short* __restrict__ vb, int* __restrict__ flagW) {
    if (blockIdx.x == 0 && blockIdx.y == 0 && threadIdx.x < 256)
        flagW[threadIdx.x] = 0;
    int fp32 = block_detect_fp32((const unsigned short*)WqR);
    __shared__ __align__(16) unsigned short As[64][136];
    __shared__ __align__(16) unsigned short Bs[64][136];
    int nb = blockIdx.x, mb = blockIdx.y;
    const void* Braw; unsigned short* Cout; int ldc, col0, br0;
    if (nb < 4)      { Braw = WqR; br0 = nb * 64;       Cout = qb; ldc = 256;  col0 = nb * 64; }
    else if (nb < 8) { Braw = WkR; br0 = (nb - 4) * 64; Cout = kb; ldc = 256;  col0 = (nb - 4) * 64; }
    else             { Braw = WvR; br0 = (nb - 8) * 64; Cout = vb; ldc = 1024; col0 = (nb - 8) * 64; }

    floatx4 acc[4];
    gemm64_body(As, Bs, hidR, fp32, mb * 64, Braw, fp32, br0, acc);

    int wave = threadIdx.x >> 6, lane = threadIdx.x & 63;
    int ml = lane & 15, q4 = lane >> 4;
    int mq = (wave >> 1) * 32, nq = (wave & 1) * 32;
    #pragma unroll
    for (int mi = 0; mi < 2; ++mi)
        #pragma unroll
        for (int ni = 0; ni < 2; ++ni) {
            floatx4 a = acc[mi * 2 + ni];
            int nloc = nq + ni * 16 + ml;
            #pragma unroll
            for (int r4 = 0; r4 < 4; ++r4) {
                int row = mb * 64 + mq + mi * 16 + q4 * 4 + r4;
                Cout[(size_t)row * ldc + col0 + nloc] = f2bf(a[r4]);
            }
        }
}

// ---------------------------------------------------------------------------
// Kernel 2: flash-style quadratic polynomial attention, kv-range split 2-way.
// S(l,t) = 1 + (q.k)/4 + (q.k)^2/32, causal; y = S V / (S 1).
// Block (h, c, s): Q rows [64c, +64); s=0 handles kv tiles [0, half),
// s=1 handles [half, c] (incl. diagonal), half = (c+1)>>1. Critical path
// drops 16 -> 8 tiles and grid 256 -> 512 (2 blocks/CU, 8 waves/CU).
// Both halves write fp32 partial num/den to ws; the SECOND block to finish
// (device-scope atomic flag) combines (own regs + other's partials) and
// writes y. No spin-waiting, so no co-residency assumption.
// ---------------------------------------------------------------------------
__global__ __launch_bounds__(256) void flash_attn(
    const unsigned short* __restrict__ qb, const unsigned short* __restrict__ kb,
    const unsigned short* __restrict__ vb, unsigned short* __restrict__ ybB,
    float* __restrict__ numW, float* __restrict__ denW, int* __restrict__ flagW) {
    int idx = blockIdx.x & 255;          // (h, c)
    int s = blockIdx.x >> 8;             // kv-range half
    int h = idx & 15, c = idx >> 4;
    int half = (c + 1) >> 1;
    int j0 = s ? half : 0;
    int j1 = s ? c : half - 1;           // inclusive; s=0 empty when c==0
    int l0 = c * CHUNK;
    __shared__ __align__(16) unsigned short qs[64][40];
    __shared__ __align__(16) unsigned short ksm[64][40];
    __shared__ __align__(16) unsigned short vT[80][72];   // rows 0..63 v^T, 64 ones
    __shared__ __align__(16) unsigned short P[64][72];
    __shared__ int turn;
    int t = threadIdx.x, lane = t & 63, wave = t >> 6;
    int ml = lane & 15, q4 = lane >> 4;
    int m0 = wave * 16;
    int sm = t >> 2, si4 = (t & 3) * 4, scc = (t & 3) * 16;

    // ---- one-time staging: q rows (zero-padded K=32), vT pad rows
    {
        *(ushort4*)&qs[sm][si4] = *(const ushort4*)&qb[(size_t)(l0 + sm) * 256 + h * 16 + si4];
        ushort4 z = {0, 0, 0, 0};
        *(ushort4*)&qs[sm][16 + si4]  = z;
        *(ushort4*)&ksm[sm][16 + si4] = z;   // k pad, persists across tiles
    }
    if (t < 64) {
        vT[64][t] = 0x3F80;   // 1.0 bf16 (denominator row)
        #pragma unroll
        for (int i = 65; i < 80; ++i) vT[i][t] = 0;
    }

    auto load_kv = [&](int j, ushort4& kr, ushort4 vr[4]) {
        kr = *(const ushort4*)&kb[(size_t)(j * 64 + sm) * 256 + h * 16 + si4];
        #pragma unroll
        for (int u = 0; u < 4; ++u)
            vr[u] = *(const ushort4*)&vb[(size_t)(j * 64 + sm) * 1024 + h * 64 + scc + u * 4];
    };

    floatx4 acc[5];
    #pragma unroll
    for (int i = 0; i < 5; ++i) acc[i] = (floatx4){0.f, 0.f, 0.f, 0.f};

    ushort4 kr, vr[4], kr2, vr2[4];
    if (j0 <= j1) {
        load_kv(j0, kr, vr);
        for (int j = j0; j <= j1; ++j) {
            // ---- write prefetched k_j / v_j^T to LDS
            {
                *(ushort4*)&ksm[sm][si4] = kr;
                unsigned short tmp[16];
                #pragma unroll
                for (int u = 0; u < 4; ++u) *(ushort4*)&tmp[u * 4] = vr[u];
                #pragma unroll
                for (int u = 0; u < 16; ++u) vT[scc + u][sm] = tmp[u];
            }
            __syncthreads();   // staging visible (also covers qs on first iter)
            if (j < j1) load_kv(j + 1, kr2, vr2);   // overlap with MFMAs below

            // ---- scores S = q k^T (K=32, zero-padded), poly + causal -> P
            short8 aq = *(const short8*)&qs[m0 + ml][q4 * 8];
            bool diag = (j == c);
            #pragma unroll
            for (int nt = 0; nt < 4; ++nt) {
                short8 bk = *(const short8*)&ksm[nt * 16 + ml][q4 * 8];
                floatx4 s4 = {0.f, 0.f, 0.f, 0.f};
                s4 = MFMA(aq, bk, s4);
                int tt = nt * 16 + ml;
                #pragma unroll
                for (int r = 0; r < 4; ++r) {
                    int lrow = m0 + q4 * 4 + r;
                    float sc = s4[r];
                    float p = 1.f + 0.25f * sc + 0.03125f * sc * sc;
                    if (diag && tt > lrow) p = 0.f;
                    P[lrow][tt] = f2bf(p);
                }
            }
            // P rows are wave-private (written rows m0..m0+15, read rows m0+ml):
            // no barrier needed before PV.

            // ---- PV: acc[nt] += P x vT (nt=4 ones-row -> denominator)
            #pragma unroll
            for (int k0 = 0; k0 < 64; k0 += 32) {
                short8 ap = *(const short8*)&P[m0 + ml][k0 + q4 * 8];
                #pragma unroll
                for (int nt = 0; nt < 5; ++nt) {
                    short8 bvv = *(const short8*)&vT[nt * 16 + ml][k0 + q4 * 8];
                    acc[nt] = MFMA(ap, bvv, acc[nt]);
                }
            }
            __syncthreads();   // protect ksm/vT from next tile's staging
            kr = kr2;
            #pragma unroll
            for (int u = 0; u < 4; ++u) vr[u] = vr2[u];
        }
    }

    // ---- write fp32 partials (num 64x64, den 64) for this half
    float* np = numW + ((size_t)idx * 2 + s) * 4096;
    #pragma unroll
    for (int nt = 0; nt < 4; ++nt)
        #pragma unroll
        for (int r = 0; r < 4; ++r)
            np[(m0 + q4 * 4 + r) * 64 + nt * 16 + ml] = acc[nt][r];
    if (ml == 0) {
        float* dp = denW + ((size_t)idx * 2 + s) * 64;
        #pragma unroll
        for (int r = 0; r < 4; ++r) dp[m0 + q4 * 4 + r] = acc[4][r];
    }
    __threadfence();   // partials visible device-wide before the flag bump
    if (t == 0) turn = atomicAdd(&flagW[idx], 1);
    __syncthreads();
    if (turn == 0) return;       // first arriver: partner will combine
    __threadfence();             // order: flag observed -> partner's data reads

    // ---- combine: own regs + partner's partials; y = num/den -> bf16
    int so = 1 - s;
    const float* no_ = numW + ((size_t)idx * 2 + so) * 4096;
    const float* do_ = denW + ((size_t)idx * 2 + so) * 64;
    #pragma unroll
    for (int r = 0; r < 4; ++r) {
        int lrow = m0 + q4 * 4 + r;
        float den = __shfl(acc[4][r], q4 * 16) + do_[lrow] + 1e-12f;
        float dinv = 1.f / den;
        unsigned short* yp = ybB + (size_t)(l0 + lrow) * 1024 + h * 64;
        #pragma unroll
        for (int nt = 0; nt < 4; ++nt)
            yp[nt * 16 + ml] = f2bf((acc[nt][r] + no_[lrow * 64 + nt * 16 + ml]) * dinv);
    }
}

// ---------------------------------------------------------------------------
// Kernel 3: output projection. out = y @ Wo^T (1024^3). Output dtype per
// detector.
// ---------------------------------------------------------------------------
__global__ __launch_bounds__(256) void out_gemm(
    const unsigned short* __restrict__ A, const void* __restrict__ WoR,
    void* __restrict__ outv, const unsigned short* __restrict__ wqraw) {
    int fp32 = block_detect_fp32(wqraw);
    __shared__ __align__(16) unsigned short As[64][136];
    __shared__ __align__(16) unsigned short Bs[64][136];
    int nb = blockIdx.x, mb = blockIdx.y;

    floatx4 acc[4];
    gemm64_body(As, Bs, A, 0, mb * 64, WoR, fp32, nb * 64, acc);

    int wave = threadIdx.x >> 6, lane = threadIdx.x & 63;
    int ml = lane & 15, q4 = lane >> 4;
    int mq = (wave >> 1) * 32, nq = (wave & 1) * 32;
    #pragma unroll
    for (int mi = 0; mi < 2; ++mi)
        #pragma unroll
        for (int ni = 0; ni < 2; ++ni) {
            floatx4 a = acc[mi * 2 + ni];
            int n = nb * 64 + nq + ni * 16 + ml;
            #pragma unroll
            for (int r4 = 0; r4 < 4; ++r4) {
                int row = mb * 64 + mq + mi * 16 + q4 * 4 + r4;
                size_t idx = (size_t)row * 1024 + n;
                if (fp32) ((float*)outv)[idx] = a[r4];
                else      ((unsigned short*)outv)[idx] = f2bf(a[r4]);
            }
        }
}

// ---------------------------------------------------------------------------
extern "C" void kernel_launch(void* const* d_in, const int* in_sizes, int n_in,
                              void* d_out, int out_size, void* d_ws, size_t ws_size,
                              hipStream_t stream) {
    unsigned short* us = (unsigned short*)d_ws;
    unsigned short* qbB = us + U_QB;
    unsigned short* kbB = us + U_KB;
    unsigned short* vbB = us + U_VB;
    unsigned short* ybB = us + U_YB;
    float* fws  = (float*)(us + U_END);       // byte offset 5242880, 256B-aligned
    float* numW = fws;                        // 2097152 floats
    float* denW = fws + 2097152;              // 32768 floats
    int*   flagW = (int*)(denW + 32768);      // 256 ints
    size_t need = (size_t)U_END * 2ull + (size_t)(2097152 + 32768 + 256) * 4ull;
    if (ws_size < need) return;

    qkv_gemm<<<dim3(24, 16), 256, 0, stream>>>(d_in[0], d_in[1], d_in[2], d_in[3], qbB, kbB, vbB, flagW);
    flash_attn<<<dim3(512), 256, 0, stream>>>(qbB, kbB, vbB, ybB, numW, denW, flagW);
    out_gemm<<<dim3(16, 16), 256, 0, stream>>>(ybB, d_in[4], d_out, (const unsigned short*)d_in[1]);
}

// Round 2
// 140.016 us; speedup vs baseline: 1.5734x; 1.5734x over previous
//
#include <hip/hip_runtime.h>

// Problem constants
#define LSEQ 1024
#define DMODEL 1024
#define NHEADS 16
#define FDIM 16
#define HDIM 64
#define CHUNK 64
#define NCHUNK 16

typedef __attribute__((ext_vector_type(8))) short short8;   // 8 bf16 (4 VGPRs)
typedef __attribute__((ext_vector_type(4))) float floatx4;  // MFMA acc

__device__ __forceinline__ float bf2f(unsigned short u) {
    unsigned int x = ((unsigned int)u) << 16;
    return __builtin_bit_cast(float, x);
}
__device__ __forceinline__ unsigned short f2bf(float f) {
    unsigned int x = __builtin_bit_cast(unsigned int, f);
    unsigned int r = (x + 0x7fffu + ((x >> 16) & 1u)) >> 16;
    return (unsigned short)r;
}

// Per-block dtype detector: samples 1024 ushorts of Wq. bf16 data -> exponents
// cluster tightly (bad ~0%); fp32-as-ushort -> half the samples are uniform
// mantissa bits (bad ~30%+). Returns 1 if inputs are fp32.
__device__ __forceinline__ int block_detect_fp32(const unsigned short* wq) {
    __shared__ int cnt;
    if (threadIdx.x == 0) cnt = 0;
    __syncthreads();
    int bad = 0;
    for (int i = threadIdx.x; i < 1024; i += blockDim.x) {
        int e = (wq[i] >> 7) & 0xFF;
        if (e >= 143 || (e > 0 && e <= 80)) bad++;
    }
    if (bad) atomicAdd(&cnt, bad);
    __syncthreads();
    return cnt > 128;
}

// Workspace layout (ushort indices):
//   qbB @0        (262144)   bf16 q  [1024][256]
//   kbB @262144   (262144)   bf16 k  [1024][256]
//   vbB @524288   (1048576)  bf16 v  [1024][1024]
//   ybB @1572864  (1048576)  bf16 y  [1024][1024]
//   then fp32 partials (byte offset 5242880):
//   numW  [256][2][64][64] fp32   (2097152 floats)
//   denW  [256][2][64]     fp32   (32768 floats)
#define U_QB   0
#define U_KB   262144
#define U_VB   524288
#define U_YB   1572864
#define U_END  2621440

#define MFMA(a, b, c) __builtin_amdgcn_mfma_f32_16x16x32_bf16((a), (b), (c), 0, 0, 0)

// ---------------------------------------------------------------------------
// Pipelined 64x64 GEMM tile body: C(64x64) = A[arow0:+64] @ B[brow0:+64]^T,
// lda = ldb = 1024, K = 1024, BK = 128. Iter k+1's global loads issue right
// after the LDS-ready barrier, overlapping the 16 MFMAs; the vmcnt drain
// lands at the NEXT iteration's LDS write instead of serializing each iter.
// fp32 inputs are staged with float4 (16B/lane) vector loads — the scalar
// path made a wave's load instruction scatter 64 independent 4B accesses.
// acc order: 00,01,10,11 (mi*2+ni).
// ---------------------------------------------------------------------------
__device__ __forceinline__ void gemm64_body(
    unsigned short (&As)[64][136], unsigned short (&Bs)[64][136],
    const void* Araw, int a_fp32, int arow0,
    const void* Braw, int b_fp32, int brow0, floatx4 acc[4]) {
    int t = threadIdx.x;
    int r = t >> 2, c0 = (t & 3) * 32;
    int wave = t >> 6, lane = t & 63;
    int ml = lane & 15, q4 = lane >> 4;
    int mq = (wave >> 1) * 32, nq = (wave & 1) * 32;
    #pragma unroll
    for (int i = 0; i < 4; ++i) acc[i] = (floatx4){0.f, 0.f, 0.f, 0.f};

    short8 av[4], bv[4], av2[4], bv2[4];
    auto stage = [&](int k0, short8* a, short8* b) {
        if (!a_fp32) {
            const unsigned short* Ap = (const unsigned short*)Araw + (size_t)(arow0 + r) * DMODEL + k0 + c0;
            #pragma unroll
            for (int j = 0; j < 4; ++j) a[j] = *(const short8*)(Ap + j * 8);
        } else {
            const float* Ap = (const float*)Araw + (size_t)(arow0 + r) * DMODEL + k0 + c0;
            #pragma unroll
            for (int j = 0; j < 4; ++j) {
                float4 f0 = *(const float4*)(Ap + j * 8);
                float4 f1 = *(const float4*)(Ap + j * 8 + 4);
                short8 x;
                x[0] = (short)f2bf(f0.x); x[1] = (short)f2bf(f0.y);
                x[2] = (short)f2bf(f0.z); x[3] = (short)f2bf(f0.w);
                x[4] = (short)f2bf(f1.x); x[5] = (short)f2bf(f1.y);
                x[6] = (short)f2bf(f1.z); x[7] = (short)f2bf(f1.w);
                a[j] = x;
            }
        }
        if (!b_fp32) {
            const unsigned short* Bp = (const unsigned short*)Braw + (size_t)(brow0 + r) * DMODEL + k0 + c0;
            #pragma unroll
            for (int j = 0; j < 4; ++j) b[j] = *(const short8*)(Bp + j * 8);
        } else {
            const float* Bp = (const float*)Braw + (size_t)(brow0 + r) * DMODEL + k0 + c0;
            #pragma unroll
            for (int j = 0; j < 4; ++j) {
                float4 f0 = *(const float4*)(Bp + j * 8);
                float4 f1 = *(const float4*)(Bp + j * 8 + 4);
                short8 x;
                x[0] = (short)f2bf(f0.x); x[1] = (short)f2bf(f0.y);
                x[2] = (short)f2bf(f0.z); x[3] = (short)f2bf(f0.w);
                x[4] = (short)f2bf(f1.x); x[5] = (short)f2bf(f1.y);
                x[6] = (short)f2bf(f1.z); x[7] = (short)f2bf(f1.w);
                b[j] = x;
            }
        }
    };

    stage(0, av, bv);
    for (int k0 = 0; k0 < DMODEL; k0 += 128) {
        __syncthreads();   // previous iter's LDS reads done
        #pragma unroll
        for (int j = 0; j < 4; ++j) {
            *(short8*)&As[r][c0 + j * 8] = av[j];
            *(short8*)&Bs[r][c0 + j * 8] = bv[j];
        }
        __syncthreads();   // LDS ready
        if (k0 + 128 < DMODEL) stage(k0 + 128, av2, bv2);   // overlap with MFMA
        #pragma unroll
        for (int kk = 0; kk < 4; ++kk) {
            short8 a0 = *(const short8*)&As[mq + ml][kk * 32 + q4 * 8];
            short8 a1 = *(const short8*)&As[mq + 16 + ml][kk * 32 + q4 * 8];
            short8 b0 = *(const short8*)&Bs[nq + ml][kk * 32 + q4 * 8];
            short8 b1 = *(const short8*)&Bs[nq + 16 + ml][kk * 32 + q4 * 8];
            acc[0] = MFMA(a0, b0, acc[0]); acc[1] = MFMA(a0, b1, acc[1]);
            acc[2] = MFMA(a1, b0, acc[2]); acc[3] = MFMA(a1, b1, acc[3]);
        }
        #pragma unroll
        for (int j = 0; j < 4; ++j) { av[j] = av2[j]; bv[j] = bv2[j]; }
    }
}

// ---------------------------------------------------------------------------
// Kernel 1: QKV projection. grid (24, 16): nb 0..3 q, 4..7 k, 8..23 v.
// ---------------------------------------------------------------------------
__global__ __launch_bounds__(256) void qkv_gemm(
    const void* __restrict__ hidR, const void* __restrict__ WqR,
    const void* __restrict__ WkR, const void* __restrict__ WvR,
    unsigned short* __restrict__ qb, unsigned short* __restrict__ kb,
    unsigned short* __restrict__ vb) {
    int fp32 = block_detect_fp32((const unsigned short*)WqR);
    __shared__ __align__(16) unsigned short As[64][136];
    __shared__ __align__(16) unsigned short Bs[64][136];
    int nb = blockIdx.x, mb = blockIdx.y;
    const void* Braw; unsigned short* Cout; int ldc, col0, br0;
    if (nb < 4)      { Braw = WqR; br0 = nb * 64;       Cout = qb; ldc = 256;  col0 = nb * 64; }
    else if (nb < 8) { Braw = WkR; br0 = (nb - 4) * 64; Cout = kb; ldc = 256;  col0 = (nb - 4) * 64; }
    else             { Braw = WvR; br0 = (nb - 8) * 64; Cout = vb; ldc = 1024; col0 = (nb - 8) * 64; }

    floatx4 acc[4];
    gemm64_body(As, Bs, hidR, fp32, mb * 64, Braw, fp32, br0, acc);

    int wave = threadIdx.x >> 6, lane = threadIdx.x & 63;
    int ml = lane & 15, q4 = lane >> 4;
    int mq = (wave >> 1) * 32, nq = (wave & 1) * 32;
    #pragma unroll
    for (int mi = 0; mi < 2; ++mi)
        #pragma unroll
        for (int ni = 0; ni < 2; ++ni) {
            floatx4 a = acc[mi * 2 + ni];
            int nloc = nq + ni * 16 + ml;
            #pragma unroll
            for (int r4 = 0; r4 < 4; ++r4) {
                int row = mb * 64 + mq + mi * 16 + q4 * 4 + r4;
                Cout[(size_t)row * ldc + col0 + nloc] = f2bf(a[r4]);
            }
        }
}

// ---------------------------------------------------------------------------
// Kernel 2a: flash-style quadratic polynomial attention, kv-range split 2-way,
// FENCE-FREE. S(l,t) = 1 + (q.k)/4 + (q.k)^2/32, causal; y = S V / (S 1).
// Block (h, c, s): Q rows [64c, +64); s=0 handles kv tiles [0, half),
// s=1 handles [half, c] (incl. diagonal), half = (c+1)>>1. Critical path
// 16 -> 8 tiles, grid 256 -> 512 (2 blocks/CU, 8 waves/CU). Each block just
// writes fp32 partial num/den; the kernel boundary (stream order) is the
// sync — NO device fences / atomics (round-1's __threadfence L2
// writeback+invalidate storm was a 4.4x regression).
// ---------------------------------------------------------------------------
__global__ __launch_bounds__(256) void flash_partial(
    const unsigned short* __restrict__ qb, const unsigned short* __restrict__ kb,
    const unsigned short* __restrict__ vb,
    float* __restrict__ numW, float* __restrict__ denW) {
    int idx = blockIdx.x & 255;          // (h, c)
    int s = blockIdx.x >> 8;             // kv-range half
    int h = idx & 15, c = idx >> 4;
    int half = (c + 1) >> 1;
    int j0 = s ? half : 0;
    int j1 = s ? c : half - 1;           // inclusive; s=0 empty when c==0
    int l0 = c * CHUNK;
    __shared__ __align__(16) unsigned short qs[64][40];
    __shared__ __align__(16) unsigned short ksm[64][40];
    __shared__ __align__(16) unsigned short vT[80][72];   // rows 0..63 v^T, 64 ones
    __shared__ __align__(16) unsigned short P[64][72];
    int t = threadIdx.x, lane = t & 63, wave = t >> 6;
    int ml = lane & 15, q4 = lane >> 4;
    int m0 = wave * 16;
    int sm = t >> 2, si4 = (t & 3) * 4, scc = (t & 3) * 16;

    // ---- one-time staging: q rows (zero-padded K=32), vT pad rows
    {
        *(ushort4*)&qs[sm][si4] = *(const ushort4*)&qb[(size_t)(l0 + sm) * 256 + h * 16 + si4];
        ushort4 z = {0, 0, 0, 0};
        *(ushort4*)&qs[sm][16 + si4]  = z;
        *(ushort4*)&ksm[sm][16 + si4] = z;   // k pad, persists across tiles
    }
    if (t < 64) {
        vT[64][t] = 0x3F80;   // 1.0 bf16 (denominator row)
        #pragma unroll
        for (int i = 65; i < 80; ++i) vT[i][t] = 0;
    }

    auto load_kv = [&](int j, ushort4& kr, ushort4 vr[4]) {
        kr = *(const ushort4*)&kb[(size_t)(j * 64 + sm) * 256 + h * 16 + si4];
        #pragma unroll
        for (int u = 0; u < 4; ++u)
            vr[u] = *(const ushort4*)&vb[(size_t)(j * 64 + sm) * 1024 + h * 64 + scc + u * 4];
    };

    floatx4 acc[5];
    #pragma unroll
    for (int i = 0; i < 5; ++i) acc[i] = (floatx4){0.f, 0.f, 0.f, 0.f};

    ushort4 kr, vr[4], kr2, vr2[4];
    if (j0 <= j1) {
        load_kv(j0, kr, vr);
        for (int j = j0; j <= j1; ++j) {
            // ---- write prefetched k_j / v_j^T to LDS
            {
                *(ushort4*)&ksm[sm][si4] = kr;
                unsigned short tmp[16];
                #pragma unroll
                for (int u = 0; u < 4; ++u) *(ushort4*)&tmp[u * 4] = vr[u];
                #pragma unroll
                for (int u = 0; u < 16; ++u) vT[scc + u][sm] = tmp[u];
            }
            __syncthreads();   // staging visible (also covers qs on first iter)
            if (j < j1) load_kv(j + 1, kr2, vr2);   // overlap with MFMAs below

            // ---- scores S = q k^T (K=32, zero-padded), poly + causal -> P
            short8 aq = *(const short8*)&qs[m0 + ml][q4 * 8];
            bool diag = (j == c);
            #pragma unroll
            for (int nt = 0; nt < 4; ++nt) {
                short8 bk = *(const short8*)&ksm[nt * 16 + ml][q4 * 8];
                floatx4 s4 = {0.f, 0.f, 0.f, 0.f};
                s4 = MFMA(aq, bk, s4);
                int tt = nt * 16 + ml;
                #pragma unroll
                for (int r = 0; r < 4; ++r) {
                    int lrow = m0 + q4 * 4 + r;
                    float sc = s4[r];
                    float p = 1.f + 0.25f * sc + 0.03125f * sc * sc;
                    if (diag && tt > lrow) p = 0.f;
                    P[lrow][tt] = f2bf(p);
                }
            }
            // P rows are wave-private (written rows m0..m0+15, read rows m0+ml):
            // no barrier needed before PV.

            // ---- PV: acc[nt] += P x vT (nt=4 ones-row -> denominator)
            #pragma unroll
            for (int k0 = 0; k0 < 64; k0 += 32) {
                short8 ap = *(const short8*)&P[m0 + ml][k0 + q4 * 8];
                #pragma unroll
                for (int nt = 0; nt < 5; ++nt) {
                    short8 bvv = *(const short8*)&vT[nt * 16 + ml][k0 + q4 * 8];
                    acc[nt] = MFMA(ap, bvv, acc[nt]);
                }
            }
            __syncthreads();   // protect ksm/vT from next tile's staging
            kr = kr2;
            #pragma unroll
            for (int u = 0; u < 4; ++u) vr[u] = vr2[u];
        }
    }

    // ---- write fp32 partials (num 64x64, den 64) for this half
    float* np = numW + ((size_t)idx * 2 + s) * 4096;
    #pragma unroll
    for (int nt = 0; nt < 4; ++nt)
        #pragma unroll
        for (int r = 0; r < 4; ++r)
            np[(m0 + q4 * 4 + r) * 64 + nt * 16 + ml] = acc[nt][r];
    if (ml == 0) {
        float* dp = denW + ((size_t)idx * 2 + s) * 64;
        #pragma unroll
        for (int r = 0; r < 4; ++r) dp[m0 + q4 * 4 + r] = acc[4][r];
    }
}

// ---------------------------------------------------------------------------
// Kernel 2b: combine the two kv-halves and normalize: y = (n0+n1)/(d0+d1+eps).
// Grid 256 (one block per (h,c)), 256 threads; thread t -> row t>>2,
// cols (t&3)*16 .. +16. ~10 MB traffic, ~3 us.
// ---------------------------------------------------------------------------
__global__ __launch_bounds__(256) void attn_combine(
    const float* __restrict__ numW, const float* __restrict__ denW,
    unsigned short* __restrict__ ybB) {
    int idx = blockIdx.x;
    int h = idx & 15, c = idx >> 4;
    int l0 = c * CHUNK;
    int t = threadIdx.x;
    int row = t >> 2, col0 = (t & 3) * 16;
    const float* n0 = numW + (size_t)idx * 2 * 4096 + row * 64 + col0;
    const float* n1 = n0 + 4096;
    const float* dp = denW + (size_t)idx * 2 * 64 + row;
    float den = dp[0] + dp[64] + 1e-12f;
    float dinv = 1.f / den;
    short8 o0, o1;
    #pragma unroll
    for (int u = 0; u < 8; ++u)  o0[u] = (short)f2bf((n0[u] + n1[u]) * dinv);
    #pragma unroll
    for (int u = 8; u < 16; ++u) o1[u - 8] = (short)f2bf((n0[u] + n1[u]) * dinv);
    unsigned short* yp = ybB + (size_t)(l0 + row) * 1024 + h * 64 + col0;
    *(short8*)yp       = o0;
    *(short8*)(yp + 8) = o1;
}

// ---------------------------------------------------------------------------
// Kernel 3: output projection. out = y @ Wo^T (1024^3). Output dtype per
// detector.
// ---------------------------------------------------------------------------
__global__ __launch_bounds__(256) void out_gemm(
    const unsigned short* __restrict__ A, const void* __restrict__ WoR,
    void* __restrict__ outv, const unsigned short* __restrict__ wqraw) {
    int fp32 = block_detect_fp32(wqraw);
    __shared__ __align__(16) unsigned short As[64][136];
    __shared__ __align__(16) unsigned short Bs[64][136];
    int nb = blockIdx.x, mb = blockIdx.y;

    floatx4 acc[4];
    gemm64_body(As, Bs, A, 0, mb * 64, WoR, fp32, nb * 64, acc);

    int wave = threadIdx.x >> 6, lane = threadIdx.x & 63;
    int ml = lane & 15, q4 = lane >> 4;
    int mq = (wave >> 1) * 32, nq = (wave & 1) * 32;
    #pragma unroll
    for (int mi = 0; mi < 2; ++mi)
        #pragma unroll
        for (int ni = 0; ni < 2; ++ni) {
            floatx4 a = acc[mi * 2 + ni];
            int n = nb * 64 + nq + ni * 16 + ml;
            #pragma unroll
            for (int r4 = 0; r4 < 4; ++r4) {
                int row = mb * 64 + mq + mi * 16 + q4 * 4 + r4;
                size_t idx = (size_t)row * 1024 + n;
                if (fp32) ((float*)outv)[idx] = a[r4];
                else      ((unsigned short*)outv)[idx] = f2bf(a[r4]);
            }
        }
}

// ---------------------------------------------------------------------------
extern "C" void kernel_launch(void* const* d_in, const int* in_sizes, int n_in,
                              void* d_out, int out_size, void* d_ws, size_t ws_size,
                              hipStream_t stream) {
    unsigned short* us = (unsigned short*)d_ws;
    unsigned short* qbB = us + U_QB;
    unsigned short* kbB = us + U_KB;
    unsigned short* vbB = us + U_VB;
    unsigned short* ybB = us + U_YB;
    float* fws  = (float*)(us + U_END);       // byte offset 5242880, 256B-aligned
    float* numW = fws;                        // 2097152 floats
    float* denW = fws + 2097152;              // 32768 floats
    size_t need = (size_t)U_END * 2ull + (size_t)(2097152 + 32768) * 4ull;
    if (ws_size < need) return;

    qkv_gemm<<<dim3(24, 16), 256, 0, stream>>>(d_in[0], d_in[1], d_in[2], d_in[3], qbB, kbB, vbB);
    flash_partial<<<dim3(512), 256, 0, stream>>>(qbB, kbB, vbB, numW, denW);
    attn_combine<<<dim3(256), 256, 0, stream>>>(numW, denW, ybB);
    out_gemm<<<dim3(16, 16), 256, 0, stream>>>(ybB, d_in[4], d_out, (const unsigned short*)d_in[1]);
}